// Round 1
// 305.238 us; speedup vs baseline: 1.0010x; 1.0010x over previous
//
#include <hip/hip_runtime.h>
#include <math.h>

#define N_NODES 100000
#define N_EDGES 1600000
#define IN_C    128
#define HID     256
#define KEIG    64
#define OUT_C   16

#define NPB      256
#define NBUCKET  ((N_NODES + NPB - 1) / NPB)             // 391
#define EDGE_TILE 4096
#define NTILE    ((N_EDGES + EDGE_TILE - 1) / EDGE_TILE) // 391
#define CAP      8960

#define TRANS_BLOCKS   ((N_NODES + 63) / 64)             // 1563
#define GATHER_BLOCKS  2048
#define CUT_BLOCKS     2048
#define SSP_BLOCKS     512
#define OUTG_BLOCKS    384
// interleaved tail: period 23 = 16 cut + 4 ss + 3 out, x128 groups
#define TAIL_BLOCKS    (128 * 23)                        // 2944

typedef __attribute__((ext_vector_type(8))) short short8;
typedef __attribute__((ext_vector_type(4))) float f32x4;
typedef __attribute__((ext_vector_type(2))) float f32x2;

__device__ __forceinline__ float wave_sum(float v) {
#pragma unroll
    for (int m = 32; m; m >>= 1) v += __shfl_xor(v, m, 64);
    return v;
}
__device__ __forceinline__ float bf2f(unsigned int u) {
    return __uint_as_float((u & 0xffffu) << 16);
}
__device__ __forceinline__ unsigned short f2bf(float f) {
    unsigned int u = __float_as_uint(f);
    u += 0x7fff + ((u >> 16) & 1);
    return (unsigned short)(u >> 16);
}
__device__ __forceinline__ unsigned char f2fp8(float f) {
    int p = __builtin_amdgcn_cvt_pk_fp8_f32(f, f, 0, false);
    return (unsigned char)(p & 0xff);
}

#define FMA4(P, s, W) \
    P.x = fmaf(s, W.x, P.x); P.y = fmaf(s, W.y, P.y); \
    P.z = fmaf(s, W.z, P.z); P.w = fmaf(s, W.w, P.w);

// lane layout for gathers: c = lane&15 owns dims [4c..4c+3], q = lane>>4 is the
// edge subgroup. One dword vector load covers 4 edges x 64 dims per wave instr.
#define GSEL(RR) (q == 0 ? RR.x : q == 1 ? RR.y : q == 2 ? RR.z : RR.w)

#define GATHER4V(TBL, DST) do {                                                  \
    int4 ra_ = *(const int4*)(csr_row + ps + j);                                 \
    int r0_ = GSEL(ra_);                                                         \
    unsigned u0_ = *(const unsigned*)(TBL + (unsigned)r0_ * 64u + cb);           \
    f32x2 p_;                                                                    \
    p_ = __builtin_amdgcn_cvt_pk_f32_fp8(u0_, false); DST.x += p_.x; DST.y += p_.y; \
    p_ = __builtin_amdgcn_cvt_pk_f32_fp8(u0_, true);  DST.z += p_.x; DST.w += p_.y; \
} while (0)

#define GATHER16V(TBL, DST) do {                                                 \
    int4 ra_ = *(const int4*)(csr_row + ps + j);                                 \
    int4 rb_ = *(const int4*)(csr_row + ps + j + 4);                             \
    int4 rc_ = *(const int4*)(csr_row + ps + j + 8);                             \
    int4 rd_ = *(const int4*)(csr_row + ps + j + 12);                            \
    int r0_ = GSEL(ra_), r1_ = GSEL(rb_), r2_ = GSEL(rc_), r3_ = GSEL(rd_);      \
    unsigned u0_ = *(const unsigned*)(TBL + (unsigned)r0_ * 64u + cb);           \
    unsigned u1_ = *(const unsigned*)(TBL + (unsigned)r1_ * 64u + cb);           \
    unsigned u2_ = *(const unsigned*)(TBL + (unsigned)r2_ * 64u + cb);           \
    unsigned u3_ = *(const unsigned*)(TBL + (unsigned)r3_ * 64u + cb);           \
    f32x2 p_;                                                                    \
    p_ = __builtin_amdgcn_cvt_pk_f32_fp8(u0_, false); DST.x += p_.x; DST.y += p_.y; \
    p_ = __builtin_amdgcn_cvt_pk_f32_fp8(u0_, true);  DST.z += p_.x; DST.w += p_.y; \
    p_ = __builtin_amdgcn_cvt_pk_f32_fp8(u1_, false); DST.x += p_.x; DST.y += p_.y; \
    p_ = __builtin_amdgcn_cvt_pk_f32_fp8(u1_, true);  DST.z += p_.x; DST.w += p_.y; \
    p_ = __builtin_amdgcn_cvt_pk_f32_fp8(u2_, false); DST.x += p_.x; DST.y += p_.y; \
    p_ = __builtin_amdgcn_cvt_pk_f32_fp8(u2_, true);  DST.z += p_.x; DST.w += p_.y; \
    p_ = __builtin_amdgcn_cvt_pk_f32_fp8(u3_, false); DST.x += p_.x; DST.y += p_.y; \
    p_ = __builtin_amdgcn_cvt_pk_f32_fp8(u3_, true);  DST.z += p_.x; DST.w += p_.y; \
} while (0)

// ---------------- small precompute ----------------
__global__ void prep_weff(const float* __restrict__ mlpxW, const float* __restrict__ mlpxb,
                          const float* __restrict__ finW, const float* __restrict__ finb,
                          float* __restrict__ Weff, float* __restrict__ beff,
                          int* __restrict__ bcnt, unsigned char* __restrict__ WT8,
                          unsigned char* __restrict__ S8, int* __restrict__ gpad) {
    int t = blockIdx.x * blockDim.x + threadIdx.x;
    const int NW = (IN_C + KEIG) * OUT_C;
    if (t < NW) {
        int k = t >> 4, o = t & 15;
        float acc;
        if (k < IN_C) {
            acc = 0.f;
            for (int c = 0; c < HID; ++c)
                acc += mlpxW[c * IN_C + k] * finW[o * (HID + KEIG) + c];
        } else {
            acc = finW[o * (HID + KEIG) + HID + (k - IN_C)];
        }
        Weff[k * OUT_C + o] = acc;
    }
    int tb = t - NW;
    if (tb >= 0 && tb < OUT_C) {
        float acc = finb[tb];
        for (int c = 0; c < HID; ++c) acc += mlpxb[c] * finW[tb * (HID + KEIG) + c];
        beff[tb] = acc;
    }
    int tz = t - (NW + OUT_C);
    if (tz >= 0 && tz <= NBUCKET) bcnt[tz] = 0;
    int tp = t - (NW + OUT_C + NBUCKET + 1);
    if (tp >= 0 && tp < 16) {
        ((int*)(WT8 + (size_t)N_NODES * 64))[tp] = 0;
        ((int*)(S8 + (size_t)N_NODES * 64))[tp] = 0;
        if (tp == 0) *gpad = 0;
    }
}

// ---------------- fused: transpose_w | bucket_hist ----------------
__global__ __launch_bounds__(256) void fused_prep(const float* __restrict__ W,
                                                  unsigned char* __restrict__ WT8,
                                                  const int* __restrict__ ei,
                                                  int* __restrict__ bcnt) {
    __shared__ __align__(16) char sm[64 * 65 * 4];
    int t = threadIdx.x;
    if (blockIdx.x < TRANS_BLOCKS) {
        float (*tile)[65] = (float (*)[65])sm;
        int n0 = blockIdx.x * 64;
        int tn = t & 63, tq = t >> 6;
#pragma unroll
        for (int kk = 0; kk < 16; ++kk) {
            int k = tq * 16 + kk;
            int n = n0 + tn;
            tile[k][tn] = (n < N_NODES) ? W[(long long)k * N_NODES + n] : 0.f;
        }
        __syncthreads();
        int tk = t & 63;
#pragma unroll
        for (int ii = 0; ii < 16; ++ii) {
            int n = n0 + tq * 16 + ii;
            if (n < N_NODES) WT8[(unsigned)n * 64u + tk] = f2fp8(tile[tk][tq * 16 + ii] * 32.f);
        }
    } else {
        int* h = (int*)sm;
        for (int i = t; i < NBUCKET; i += 256) h[i] = 0;
        __syncthreads();
        int tile_i = blockIdx.x - TRANS_BLOCKS;
        int e0 = tile_i * EDGE_TILE;
        int e1 = min(e0 + EDGE_TILE, N_EDGES);
        for (int e = e0 + t; e < e1; e += 256)
            atomicAdd(&h[ei[N_EDGES + e] >> 8], 1);
        __syncthreads();
        for (int i = t; i < NBUCKET; i += 256)
            if (h[i]) atomicAdd(&bcnt[i], h[i]);
    }
}

__global__ void bucket_scan(const int* __restrict__ bcnt, int* __restrict__ bbase,
                            int* __restrict__ bcur) {
    __shared__ int sh[512];
    int t = threadIdx.x;
    int v = (t < NBUCKET) ? bcnt[t] : 0;
    sh[t] = v;
    __syncthreads();
    for (int d = 1; d < 512; d <<= 1) {
        int u = (t >= d) ? sh[t - d] : 0;
        __syncthreads();
        sh[t] += u;
        __syncthreads();
    }
    if (t < NBUCKET) { bbase[t] = sh[t] - v; bcur[t] = sh[t] - v; }
    if (t == 0) bbase[NBUCKET] = N_EDGES;
}

__global__ void bucket_scatter(const int* __restrict__ ei, int* __restrict__ bcur,
                               int* __restrict__ ebuf) {
    __shared__ int h[NBUCKET];
    __shared__ int gb[NBUCKET];
    __shared__ int lpre[NBUCKET];
    __shared__ int psum[256];
    __shared__ int stage[EDGE_TILE];
    __shared__ short bkt[EDGE_TILE];
    int t = threadIdx.x;
    for (int i = t; i < NBUCKET; i += 256) h[i] = 0;
    __syncthreads();
    int e0 = blockIdx.x * EDGE_TILE;
    int e1 = min(e0 + EDGE_TILE, N_EDGES);
    int nt = e1 - e0;
    for (int e = e0 + t; e < e1; e += 256)
        atomicAdd(&h[ei[N_EDGES + e] >> 8], 1);
    __syncthreads();
    int a0 = (2 * t < NBUCKET) ? h[2 * t] : 0;
    int a1 = (2 * t + 1 < NBUCKET) ? h[2 * t + 1] : 0;
    psum[t] = a0 + a1;
    __syncthreads();
    for (int d = 1; d < 256; d <<= 1) {
        int u = (t >= d) ? psum[t - d] : 0;
        __syncthreads();
        psum[t] += u;
        __syncthreads();
    }
    int base = (t == 0) ? 0 : psum[t - 1];
    if (2 * t < NBUCKET) lpre[2 * t] = base;
    if (2 * t + 1 < NBUCKET) lpre[2 * t + 1] = base + a0;
    __syncthreads();
    for (int i = t; i < NBUCKET; i += 256) {
        int c = h[i];
        gb[i] = c ? atomicAdd(&bcur[i], c) : 0;
        h[i] = lpre[i];
    }
    __syncthreads();
    for (int e = e0 + t; e < e1; e += 256) {
        int r = ei[e];
        int c = ei[N_EDGES + e];
        int b = c >> 8;
        int slot = atomicAdd(&h[b], 1);
        stage[slot] = r | ((c & 255) << 17);
        bkt[slot] = (short)b;
    }
    __syncthreads();
    for (int s = t; s < nt; s += 256) {
        int b = bkt[s];
        ebuf[gb[b] + s - lpre[b]] = stage[s];
    }
}

// csr_build: pad-4 segments (gathers work on 4-edge granularity now)
__global__ void csr_build(const int* __restrict__ ebuf, const int* __restrict__ bbase,
                          int2* __restrict__ nodei,
                          int* __restrict__ csr_row, int* __restrict__ gpad) {
    __shared__ int hist[NPB];
    __shared__ int sh[NPB];
    __shared__ int curs[NPB];
    __shared__ int staged[CAP];
    __shared__ int pbase_sh;
    int b = blockIdx.x;
    int t = threadIdx.x;
    int s0 = bbase[b], s1 = bbase[b + 1];
    hist[t] = 0;
    __syncthreads();
    for (int i = s0 + t; i < s1; i += 256)
        atomicAdd(&hist[ebuf[i] >> 17], 1);
    __syncthreads();
    int v = hist[t];
    int pv = (v + 3) & ~3;
    sh[t] = pv;
    __syncthreads();
    for (int d = 1; d < 256; d <<= 1) {
        int u = (t >= d) ? sh[t - d] : 0;
        __syncthreads();
        sh[t] += u;
        __syncthreads();
    }
    int pexcl = sh[t] - pv;
    int pt = sh[255];
    if (t == 0) pbase_sh = atomicAdd(gpad, pt);
    __syncthreads();
    int pbase = pbase_sh;
    int node = b * NPB + t;
    if (node < N_NODES) nodei[node] = make_int2(v, pbase + pexcl);
    curs[t] = pexcl;
    __syncthreads();
    if (pt <= CAP) {
        for (int i = t; i < pt; i += 256) staged[i] = N_NODES;
        __syncthreads();
        for (int i = s0 + t; i < s1; i += 256) {
            int pk = ebuf[i];
            int pos = atomicAdd(&curs[pk >> 17], 1);
            staged[pos] = pk & 0x1FFFF;
        }
        __syncthreads();
        for (int i = t; i < pt; i += 256) csr_row[pbase + i] = staged[i];
    } else {
        for (int i = t; i < pt; i += 256) csr_row[pbase + i] = N_NODES;
        __syncthreads();
        for (int i = s0 + t; i < s1; i += 256) {
            int pk = ebuf[i];
            int pos = atomicAdd(&curs[pk >> 17], 1);
            csr_row[pbase + pos] = pk & 0x1FFFF;
        }
    }
}

// ---------------- pass 1: dword fp8 gather (4 edges/instr) + softmax + deg_term ---
__global__ void gather_softmax(const int2* __restrict__ nodei,
                               const int* __restrict__ csr_row,
                               const unsigned char* __restrict__ WT8,
                               const float* __restrict__ MLPb,
                               unsigned short* __restrict__ Sb,
                               unsigned char* __restrict__ S8,
                               float* __restrict__ dtp) {
    int lane = threadIdx.x & 63;
    int q = lane >> 4;
    unsigned cb = (unsigned)(lane & 15) * 4u;
    int wib = __builtin_amdgcn_readfirstlane(threadIdx.x >> 6);
    int gw = blockIdx.x * 4 + wib;
    int nw = gridDim.x * 4;
    f32x4 bias = *(const f32x4*)(MLPb + (lane & 15) * 4);
    float dacc = 0.f;
    for (int n = gw; n < N_NODES; n += nw) {
        int2 di = nodei[n];
        int deg = __builtin_amdgcn_readfirstlane(di.x);
        int ps  = __builtin_amdgcn_readfirstlane(di.y);
        int plen = (deg + 3) & ~3;
        f32x4 acc = {0.f, 0.f, 0.f, 0.f};
        int j = 0;
        for (; j + 16 <= plen; j += 16) { GATHER16V(WT8, acc); }
        for (; j < plen; j += 4) { GATHER4V(WT8, acc); }
        // combine the 4 edge-subgroup partials (lanes q=0..3)
#pragma unroll
        for (int mm = 16; mm < 64; mm <<= 1) {
            acc.x += __shfl_xor(acc.x, mm, 64);
            acc.y += __shfl_xor(acc.y, mm, 64);
            acc.z += __shfl_xor(acc.z, mm, 64);
            acc.w += __shfl_xor(acc.w, mm, 64);
        }
        float ax = bias.x + acc.x * 0.03125f;
        float ay = bias.y + acc.y * 0.03125f;
        float az = bias.z + acc.z * 0.03125f;
        float aw = bias.w + acc.w * 0.03125f;
        float m4 = fmaxf(fmaxf(ax, ay), fmaxf(az, aw));
#pragma unroll
        for (int mm = 1; mm < 16; mm <<= 1) m4 = fmaxf(m4, __shfl_xor(m4, mm, 64));
        float ex = __expf(ax - m4), ey = __expf(ay - m4);
        float ez = __expf(az - m4), ew = __expf(aw - m4);
        float s4 = (ex + ey) + (ez + ew);
#pragma unroll
        for (int mm = 1; mm < 16; mm <<= 1) s4 += __shfl_xor(s4, mm, 64);
        float inv = 1.f / s4;
        float sx = ex * inv, sy = ey * inv, sz = ez * inv, sw = ew * inv;
        if (q == 0) {
            unsigned lo = (unsigned)f2bf(sx) | ((unsigned)f2bf(sy) << 16);
            unsigned hi = (unsigned)f2bf(sz) | ((unsigned)f2bf(sw) << 16);
            *(uint2*)(Sb + (unsigned)n * 64u + cb) = make_uint2(lo, hi);
            int p8 = __builtin_amdgcn_cvt_pk_fp8_f32(sx * 64.f, sy * 64.f, 0, false);
            p8 = __builtin_amdgcn_cvt_pk_fp8_f32(sz * 64.f, sw * 64.f, p8, true);
            *(unsigned*)(S8 + (unsigned)n * 64u + cb) = (unsigned)p8;
        }
        dacc += (float)deg * ((sx * sx + sy * sy) + (sz * sz + sw * sw));
    }
    dacc = wave_sum(dacc);   // 4x replicated across q-groups -> scale 0.25
    __shared__ float red[4];
    if (lane == 0) red[wib] = dacc * 0.25f;
    __syncthreads();
    if (threadIdx.x == 0) dtp[blockIdx.x] = red[0] + red[1] + red[2] + red[3];
}

// ---------------- fused tail, role-interleaved: 16 cut | 4 ss | 3 out per 23 ----
__global__ __launch_bounds__(256) void fused_tail(
        const int2* __restrict__ nodei,
        const int* __restrict__ csr_row,
        const unsigned short* __restrict__ Sb, const unsigned char* __restrict__ S8,
        float* __restrict__ cutp, float* __restrict__ ssp,
        const float* __restrict__ x, const float* __restrict__ Weff,
        const float* __restrict__ beff, float* __restrict__ out) {
    __shared__ __align__(16) char sm[768 * 16 + 64];
    int t = threadIdx.x;
    int grp = blockIdx.x / 23;
    int r23 = blockIdx.x % 23;

    if (r23 < 16) {
        // ---- cut: dot(S[n], sum_{r in adj(n)} S[r]) via dword fp8 gathers ----
        int bid = grp * 16 + r23;                 // 0..2047
        int lane = t & 63;
        int q = lane >> 4;
        unsigned cb = (unsigned)(lane & 15) * 4u;
        int wib = __builtin_amdgcn_readfirstlane(t >> 6);
        int gw = bid * 4 + wib;
        int nw = CUT_BLOCKS * 4;
        float acc = 0.f;
        for (int n = gw; n < N_NODES; n += nw) {
            int2 di = nodei[n];
            int deg = __builtin_amdgcn_readfirstlane(di.x);
            int ps  = __builtin_amdgcn_readfirstlane(di.y);
            uint2 su = *(const uint2*)(Sb + (unsigned)n * 64u + cb);
            int plen = (deg + 3) & ~3;
            f32x4 g = {0.f, 0.f, 0.f, 0.f};
            int j = 0;
            for (; j + 16 <= plen; j += 16) { GATHER16V(S8, g); }
            for (; j < plen; j += 4) { GATHER4V(S8, g); }
            // q-group partials sum across lanes in wave_sum below (no replication)
            acc += bf2f(su.x) * g.x + bf2f(su.x >> 16) * g.y
                 + bf2f(su.y) * g.z + bf2f(su.y >> 16) * g.w;
        }
        acc = wave_sum(acc);
        float* red = (float*)sm;
        if (lane == 0) red[wib] = acc * 0.015625f;
        __syncthreads();
        if (t == 0) cutp[bid] = red[0] + red[1] + red[2] + red[3];
    } else if (r23 < 20) {
        // ---- SS = S^T S via MFMA ----
        int bid2 = grp * 4 + (r23 - 16);          // 0..511
        unsigned short (*Sr)[66] = (unsigned short (*)[66])sm;
        int lane = t & 63;
        int w = t >> 6;
        int m = lane & 15;
        int quad = lane >> 4;
        int srow = t >> 3;
        int spart = t & 7;
        f32x4 a0 = {0.f,0.f,0.f,0.f}, a1 = {0.f,0.f,0.f,0.f};
        f32x4 a2 = {0.f,0.f,0.f,0.f}, a3 = {0.f,0.f,0.f,0.f};
        for (int base = bid2 * 32; base < N_NODES; base += SSP_BLOCKS * 32) {
            const uint4* g = (const uint4*)(Sb + (long long)(base + srow) * 64 + spart * 8);
            uint4 d = *g;
            __syncthreads();
            unsigned int* rowp = (unsigned int*)&Sr[srow][0];
            rowp[spart * 4 + 0] = d.x;
            rowp[spart * 4 + 1] = d.y;
            rowp[spart * 4 + 2] = d.z;
            rowp[spart * 4 + 3] = d.w;
            __syncthreads();
            short8 f0, f1, f2, f3;
#pragma unroll
            for (int j = 0; j < 8; ++j) {
                int k = quad * 8 + j;
                f0[j] = (short)Sr[k][m];
                f1[j] = (short)Sr[k][16 + m];
                f2[j] = (short)Sr[k][32 + m];
                f3[j] = (short)Sr[k][48 + m];
            }
            short8 fa = (w == 0) ? f0 : (w == 1) ? f1 : (w == 2) ? f2 : f3;
            a0 = __builtin_amdgcn_mfma_f32_16x16x32_bf16(fa, f0, a0, 0, 0, 0);
            a1 = __builtin_amdgcn_mfma_f32_16x16x32_bf16(fa, f1, a1, 0, 0, 0);
            a2 = __builtin_amdgcn_mfma_f32_16x16x32_bf16(fa, f2, a2, 0, 0, 0);
            a3 = __builtin_amdgcn_mfma_f32_16x16x32_bf16(fa, f3, a3, 0, 0, 0);
        }
        float* dst = ssp + (size_t)bid2 * 4096;
#pragma unroll
        for (int r = 0; r < 4; ++r) {
            int row = w * 16 + quad * 4 + r;
            dst[row * 64 +  0 + m] = a0[r];
            dst[row * 64 + 16 + m] = a1[r];
            dst[row * 64 + 32 + m] = a2[r];
            dst[row * 64 + 48 + m] = a3[r];
        }
    } else {
        // ---- out: logits + log_softmax (grid-stride over rows) ----
        int obid = grp * 3 + (r23 - 20);          // 0..383
        float4* Wsh = (float4*)sm;
        float* bsh = (float*)(sm + 768 * 16);
        const float4* W4 = (const float4*)Weff;
        for (int i = t; i < 768; i += 256) Wsh[i] = W4[i];
        if (t < 16) bsh[t] = beff[t];
        __syncthreads();
        for (int r = obid * 256 + t; r < N_NODES; r += OUTG_BLOCKS * 256) {
            float4 p0 = make_float4(bsh[0], bsh[1], bsh[2], bsh[3]);
            float4 p1 = make_float4(bsh[4], bsh[5], bsh[6], bsh[7]);
            float4 p2 = make_float4(bsh[8], bsh[9], bsh[10], bsh[11]);
            float4 p3 = make_float4(bsh[12], bsh[13], bsh[14], bsh[15]);
            const float4* xr = (const float4*)(x + (long long)r * IN_C);
#pragma unroll 8
            for (int j = 0; j < 32; ++j) {
                float4 xv = xr[j];
                int k = j * 4;
                float xs[4] = {xv.x, xv.y, xv.z, xv.w};
#pragma unroll
                for (int c = 0; c < 4; ++c) {
                    float s = xs[c];
                    float4 w0 = Wsh[(k + c) * 4 + 0];
                    float4 w1 = Wsh[(k + c) * 4 + 1];
                    float4 w2 = Wsh[(k + c) * 4 + 2];
                    float4 w3 = Wsh[(k + c) * 4 + 3];
                    FMA4(p0, s, w0); FMA4(p1, s, w1); FMA4(p2, s, w2); FMA4(p3, s, w3);
                }
            }
            const uint2* sr = (const uint2*)(Sb + (long long)r * 64);
#pragma unroll 8
            for (int j = 0; j < 16; ++j) {
                uint2 u = sr[j];
                float xs[4] = {bf2f(u.x), bf2f(u.x >> 16), bf2f(u.y), bf2f(u.y >> 16)};
                int k = IN_C + j * 4;
#pragma unroll
                for (int c = 0; c < 4; ++c) {
                    float s = xs[c];
                    float4 w0 = Wsh[(k + c) * 4 + 0];
                    float4 w1 = Wsh[(k + c) * 4 + 1];
                    float4 w2 = Wsh[(k + c) * 4 + 2];
                    float4 w3 = Wsh[(k + c) * 4 + 3];
                    FMA4(p0, s, w0); FMA4(p1, s, w1); FMA4(p2, s, w2); FMA4(p3, s, w3);
                }
            }
            float m = fmaxf(fmaxf(fmaxf(p0.x, p0.y), fmaxf(p0.z, p0.w)),
                            fmaxf(fmaxf(fmaxf(p1.x, p1.y), fmaxf(p1.z, p1.w)),
                                  fmaxf(fmaxf(fmaxf(p2.x, p2.y), fmaxf(p2.z, p2.w)),
                                        fmaxf(fmaxf(p3.x, p3.y), fmaxf(p3.z, p3.w)))));
            float sum = __expf(p0.x - m) + __expf(p0.y - m) + __expf(p0.z - m) + __expf(p0.w - m)
                      + __expf(p1.x - m) + __expf(p1.y - m) + __expf(p1.z - m) + __expf(p1.w - m)
                      + __expf(p2.x - m) + __expf(p2.y - m) + __expf(p2.z - m) + __expf(p2.w - m)
                      + __expf(p3.x - m) + __expf(p3.y - m) + __expf(p3.z - m) + __expf(p3.w - m);
            float lse = m + logf(sum);
            float4* o4 = (float4*)(out + (long long)r * OUT_C);
            o4[0] = make_float4(p0.x - lse, p0.y - lse, p0.z - lse, p0.w - lse);
            o4[1] = make_float4(p1.x - lse, p1.y - lse, p1.z - lse, p1.w - lse);
            o4[2] = make_float4(p2.x - lse, p2.y - lse, p2.z - lse, p2.w - lse);
            o4[3] = make_float4(p3.x - lse, p3.y - lse, p3.z - lse, p3.w - lse);
        }
    }
}

__global__ void reduce_ss(const float* __restrict__ ssp, float* __restrict__ SS) {
    int e = blockIdx.x * blockDim.x + threadIdx.x;
    float s = 0.f;
    for (int p = 0; p < SSP_BLOCKS; ++p) s += ssp[(size_t)p * 4096 + e];
    SS[e] = s;
}

// ---------------- scalar losses ----------------
__global__ void scalars_kernel(const float* __restrict__ cutp, const float* __restrict__ dtp,
                               const float* __restrict__ SS, float* __restrict__ out) {
    __shared__ float red[256];
    int t = threadIdx.x;
    float c = 0.f;
    for (int i = t; i < CUT_BLOCKS; i += 256) c += cutp[i];
    red[t] = c; __syncthreads();
    for (int s = 128; s; s >>= 1) { if (t < s) red[t] += red[t + s]; __syncthreads(); }
    float cut = red[0]; __syncthreads();

    float d = 0.f;
    for (int i = t; i < GATHER_BLOCKS; i += 256) d += dtp[i];
    red[t] = d; __syncthreads();
    for (int s = 128; s; s >>= 1) { if (t < s) red[t] += red[t + s]; __syncthreads(); }
    float dterm = red[0]; __syncthreads();

    float ss[16];
    float sq = 0.f;
#pragma unroll
    for (int j = 0; j < 16; ++j) { ss[j] = SS[t * 16 + j]; sq += ss[j] * ss[j]; }
    red[t] = sq; __syncthreads();
    for (int s = 128; s; s >>= 1) { if (t < s) red[t] += red[t + s]; __syncthreads(); }
    float nrm = sqrtf(red[0]); __syncthreads();

    float osq = 0.f;
#pragma unroll
    for (int j = 0; j < 16; ++j) {
        int idx = t * 16 + j;
        float v = ss[j] / nrm - ((idx % 65 == 0) ? 0.125f : 0.f);
        osq += v * v;
    }
    red[t] = osq; __syncthreads();
    for (int s = 128; s; s >>= 1) { if (t < s) red[t] += red[t + s]; __syncthreads(); }
    if (t == 0) {
        float loss = -(cut / dterm) + sqrtf(red[0]);
        out[(long long)N_NODES * OUT_C] = loss;
    }
}

extern "C" void kernel_launch(void* const* d_in, const int* in_sizes, int n_in,
                              void* d_out, int out_size, void* d_ws, size_t ws_size,
                              hipStream_t stream) {
    const float* x     = (const float*)d_in[0];
    const int*   ei    = (const int*)d_in[1];
    const float* MLPW  = (const float*)d_in[2];
    const float* MLPb  = (const float*)d_in[3];
    const float* mlpxW = (const float*)d_in[4];
    const float* mlpxb = (const float*)d_in[5];
    const float* finW  = (const float*)d_in[6];
    const float* finb  = (const float*)d_in[7];
    float* out = (float*)d_out;
    char* ws = (char*)d_ws;

    unsigned char*  WT8 = (unsigned char*)ws;                                 // (N+1)*64
    unsigned char*  S8  = (unsigned char*)(ws + (size_t)(N_NODES + 1) * 64);  // (N+1)*64
    unsigned short* Sb  = (unsigned short*)(ws + (size_t)(N_NODES + 1) * 128);// N*64*2
    char* p = ws + (size_t)(N_NODES + 1) * 128 + (size_t)N_NODES * 128;
    float* ssp  = (float*)p;                                 // 512*4096 f
    float* SS   = ssp + (size_t)SSP_BLOCKS * 4096;           // 4096
    float* Weff = SS + 4096;                                 // 3072
    float* beff = Weff + 192 * 16;                           // 16
    float* cutp = beff + 16;                                 // CUT_BLOCKS
    float* dtp  = cutp + CUT_BLOCKS;                         // GATHER_BLOCKS
    int* ebuf    = (int*)(dtp + GATHER_BLOCKS);              // E
    int* csr_row = ebuf + N_EDGES;                           // E + 16N (padded, pad4 fits)
    int2* nodei  = (int2*)(csr_row + N_EDGES + 16 * N_NODES);// N int2 (deg, pstart)
    int* bcnt    = (int*)(nodei + N_NODES);                  // NBUCKET+1
    int* bbase   = bcnt + NBUCKET + 1;                       // NBUCKET+1
    int* bcur    = bbase + NBUCKET + 1;                      // NBUCKET
    int* gpad    = bcur + NBUCKET;                           // 1

    hipLaunchKernelGGL(prep_weff, dim3(16), dim3(256), 0, stream,
                       mlpxW, mlpxb, finW, finb, Weff, beff, bcnt, WT8, S8, gpad);
    hipLaunchKernelGGL(fused_prep, dim3(TRANS_BLOCKS + NTILE), dim3(256), 0, stream,
                       MLPW, WT8, ei, bcnt);
    hipLaunchKernelGGL(bucket_scan, dim3(1), dim3(512), 0, stream, bcnt, bbase, bcur);
    hipLaunchKernelGGL(bucket_scatter, dim3(NTILE), dim3(256), 0, stream, ei, bcur, ebuf);
    hipLaunchKernelGGL(csr_build, dim3(NBUCKET), dim3(256), 0, stream,
                       ebuf, bbase, nodei, csr_row, gpad);
    hipLaunchKernelGGL(gather_softmax, dim3(GATHER_BLOCKS), dim3(256), 0, stream,
                       nodei, csr_row, WT8, MLPb, Sb, S8, dtp);
    hipLaunchKernelGGL(fused_tail, dim3(TAIL_BLOCKS), dim3(256), 0, stream,
                       nodei, csr_row, Sb, S8, cutp, ssp, x, Weff, beff, out);
    hipLaunchKernelGGL(reduce_ss, dim3(16), dim3(256), 0, stream, ssp, SS);
    hipLaunchKernelGGL(scalars_kernel, dim3(1), dim3(256), 0, stream, cutp, dtp, SS, out);
}

// Round 2
// 300.182 us; speedup vs baseline: 1.0178x; 1.0168x over previous
//
#include <hip/hip_runtime.h>
#include <math.h>

#define N_NODES 100000
#define N_EDGES 1600000
#define IN_C    128
#define HID     256
#define KEIG    64
#define OUT_C   16

#define NPB      256
#define NBUCKET  ((N_NODES + NPB - 1) / NPB)             // 391
#define EDGE_TILE 4096
#define NTILE    ((N_EDGES + EDGE_TILE - 1) / EDGE_TILE) // 391
#define CAP      8960

#define TRANS_BLOCKS   ((N_NODES + 63) / 64)             // 1563
// gather: 64 contiguous nodes per block (16 per wave), bucket-aligned
#define GATHER_BLOCKS  ((N_NODES + 63) / 64)             // 1563
#define CUT_VB         1573                              // 121*13 cut virtual blocks
#define SSP_BLOCKS     484                               // 121*4
#define SSP_ALLOC      512
#define OUTG_BLOCKS    363                               // 121*3
// interleaved tail: period 20 = 13 cut + 4 ss + 3 out, x121 groups
#define TAIL_BLOCKS    (121 * 20)                        // 2420

typedef __attribute__((ext_vector_type(8))) short short8;
typedef __attribute__((ext_vector_type(4))) float f32x4;
typedef __attribute__((ext_vector_type(2))) float f32x2;

__device__ __forceinline__ float wave_sum(float v) {
#pragma unroll
    for (int m = 32; m; m >>= 1) v += __shfl_xor(v, m, 64);
    return v;
}
__device__ __forceinline__ float bf2f(unsigned int u) {
    return __uint_as_float((u & 0xffffu) << 16);
}
__device__ __forceinline__ unsigned short f2bf(float f) {
    unsigned int u = __float_as_uint(f);
    u += 0x7fff + ((u >> 16) & 1);
    return (unsigned short)(u >> 16);
}
__device__ __forceinline__ unsigned char f2fp8(float f) {
    int p = __builtin_amdgcn_cvt_pk_fp8_f32(f, f, 0, false);
    return (unsigned char)(p & 0xff);
}

#define FMA4(P, s, W) \
    P.x = fmaf(s, W.x, P.x); P.y = fmaf(s, W.y, P.y); \
    P.z = fmaf(s, W.z, P.z); P.w = fmaf(s, W.w, P.w);

// consume 4 in-flight gather dwords (16 edges x this lane's 4 dims) into ACC
#define CONS4(ACC) do { f32x2 p_;                                                   \
    p_ = __builtin_amdgcn_cvt_pk_f32_fp8(uA0, false); ACC.x += p_.x; ACC.y += p_.y; \
    p_ = __builtin_amdgcn_cvt_pk_f32_fp8(uA0, true);  ACC.z += p_.x; ACC.w += p_.y; \
    p_ = __builtin_amdgcn_cvt_pk_f32_fp8(uA1, false); ACC.x += p_.x; ACC.y += p_.y; \
    p_ = __builtin_amdgcn_cvt_pk_f32_fp8(uA1, true);  ACC.z += p_.x; ACC.w += p_.y; \
    p_ = __builtin_amdgcn_cvt_pk_f32_fp8(uA2, false); ACC.x += p_.x; ACC.y += p_.y; \
    p_ = __builtin_amdgcn_cvt_pk_f32_fp8(uA2, true);  ACC.z += p_.x; ACC.w += p_.y; \
    p_ = __builtin_amdgcn_cvt_pk_f32_fp8(uA3, false); ACC.x += p_.x; ACC.y += p_.y; \
    p_ = __builtin_amdgcn_cvt_pk_f32_fp8(uA3, true);  ACC.z += p_.x; ACC.w += p_.y; \
} while (0)

// ---------------- small precompute ----------------
__global__ void prep_weff(const float* __restrict__ mlpxW, const float* __restrict__ mlpxb,
                          const float* __restrict__ finW, const float* __restrict__ finb,
                          float* __restrict__ Weff, float* __restrict__ beff,
                          int* __restrict__ bcnt, unsigned char* __restrict__ WT8,
                          unsigned char* __restrict__ S8, int* __restrict__ gpad) {
    int t = blockIdx.x * blockDim.x + threadIdx.x;
    const int NW = (IN_C + KEIG) * OUT_C;
    if (t < NW) {
        int k = t >> 4, o = t & 15;
        float acc;
        if (k < IN_C) {
            acc = 0.f;
            for (int c = 0; c < HID; ++c)
                acc += mlpxW[c * IN_C + k] * finW[o * (HID + KEIG) + c];
        } else {
            acc = finW[o * (HID + KEIG) + HID + (k - IN_C)];
        }
        Weff[k * OUT_C + o] = acc;
    }
    int tb = t - NW;
    if (tb >= 0 && tb < OUT_C) {
        float acc = finb[tb];
        for (int c = 0; c < HID; ++c) acc += mlpxb[c] * finW[tb * (HID + KEIG) + c];
        beff[tb] = acc;
    }
    int tz = t - (NW + OUT_C);
    if (tz >= 0 && tz <= NBUCKET) bcnt[tz] = 0;
    int tp = t - (NW + OUT_C + NBUCKET + 1);
    if (tp >= 0 && tp < 16) {
        ((int*)(WT8 + (size_t)N_NODES * 64))[tp] = 0;
        ((int*)(S8 + (size_t)N_NODES * 64))[tp] = 0;
        if (tp == 0) *gpad = 0;
    }
}

// ---------------- fused: transpose_w | bucket_hist ----------------
__global__ __launch_bounds__(256) void fused_prep(const float* __restrict__ W,
                                                  unsigned char* __restrict__ WT8,
                                                  const int* __restrict__ ei,
                                                  int* __restrict__ bcnt) {
    __shared__ __align__(16) char sm[64 * 65 * 4];
    int t = threadIdx.x;
    if (blockIdx.x < TRANS_BLOCKS) {
        float (*tile)[65] = (float (*)[65])sm;
        int n0 = blockIdx.x * 64;
        int tn = t & 63, tq = t >> 6;
#pragma unroll
        for (int kk = 0; kk < 16; ++kk) {
            int k = tq * 16 + kk;
            int n = n0 + tn;
            tile[k][tn] = (n < N_NODES) ? W[(long long)k * N_NODES + n] : 0.f;
        }
        __syncthreads();
        int tk = t & 63;
#pragma unroll
        for (int ii = 0; ii < 16; ++ii) {
            int n = n0 + tq * 16 + ii;
            if (n < N_NODES) WT8[(unsigned)n * 64u + tk] = f2fp8(tile[tk][tq * 16 + ii] * 32.f);
        }
    } else {
        int* h = (int*)sm;
        for (int i = t; i < NBUCKET; i += 256) h[i] = 0;
        __syncthreads();
        int tile_i = blockIdx.x - TRANS_BLOCKS;
        int e0 = tile_i * EDGE_TILE;
        int e1 = min(e0 + EDGE_TILE, N_EDGES);
        for (int e = e0 + t; e < e1; e += 256)
            atomicAdd(&h[ei[N_EDGES + e] >> 8], 1);
        __syncthreads();
        for (int i = t; i < NBUCKET; i += 256)
            if (h[i]) atomicAdd(&bcnt[i], h[i]);
    }
}

__global__ void bucket_scan(const int* __restrict__ bcnt, int* __restrict__ bbase,
                            int* __restrict__ bcur) {
    __shared__ int sh[512];
    int t = threadIdx.x;
    int v = (t < NBUCKET) ? bcnt[t] : 0;
    sh[t] = v;
    __syncthreads();
    for (int d = 1; d < 512; d <<= 1) {
        int u = (t >= d) ? sh[t - d] : 0;
        __syncthreads();
        sh[t] += u;
        __syncthreads();
    }
    if (t < NBUCKET) { bbase[t] = sh[t] - v; bcur[t] = sh[t] - v; }
    if (t == 0) bbase[NBUCKET] = N_EDGES;
}

__global__ void bucket_scatter(const int* __restrict__ ei, int* __restrict__ bcur,
                               int* __restrict__ ebuf) {
    __shared__ int h[NBUCKET];
    __shared__ int gb[NBUCKET];
    __shared__ int lpre[NBUCKET];
    __shared__ int psum[256];
    __shared__ int stage[EDGE_TILE];
    __shared__ short bkt[EDGE_TILE];
    int t = threadIdx.x;
    for (int i = t; i < NBUCKET; i += 256) h[i] = 0;
    __syncthreads();
    int e0 = blockIdx.x * EDGE_TILE;
    int e1 = min(e0 + EDGE_TILE, N_EDGES);
    int nt = e1 - e0;
    for (int e = e0 + t; e < e1; e += 256)
        atomicAdd(&h[ei[N_EDGES + e] >> 8], 1);
    __syncthreads();
    int a0 = (2 * t < NBUCKET) ? h[2 * t] : 0;
    int a1 = (2 * t + 1 < NBUCKET) ? h[2 * t + 1] : 0;
    psum[t] = a0 + a1;
    __syncthreads();
    for (int d = 1; d < 256; d <<= 1) {
        int u = (t >= d) ? psum[t - d] : 0;
        __syncthreads();
        psum[t] += u;
        __syncthreads();
    }
    int base = (t == 0) ? 0 : psum[t - 1];
    if (2 * t < NBUCKET) lpre[2 * t] = base;
    if (2 * t + 1 < NBUCKET) lpre[2 * t + 1] = base + a0;
    __syncthreads();
    for (int i = t; i < NBUCKET; i += 256) {
        int c = h[i];
        gb[i] = c ? atomicAdd(&bcur[i], c) : 0;
        h[i] = lpre[i];
    }
    __syncthreads();
    for (int e = e0 + t; e < e1; e += 256) {
        int r = ei[e];
        int c = ei[N_EDGES + e];
        int b = c >> 8;
        int slot = atomicAdd(&h[b], 1);
        stage[slot] = r | ((c & 255) << 17);
        bkt[slot] = (short)b;
    }
    __syncthreads();
    for (int s = t; s < nt; s += 256) {
        int b = bkt[s];
        ebuf[gb[b] + s - lpre[b]] = stage[s];
    }
}

// csr_build: pad-16 segments, contiguous per bucket (nodes in t-order)
__global__ void csr_build(const int* __restrict__ ebuf, const int* __restrict__ bbase,
                          int2* __restrict__ nodei,
                          int* __restrict__ csr_row, int* __restrict__ gpad) {
    __shared__ int hist[NPB];
    __shared__ int sh[NPB];
    __shared__ int curs[NPB];
    __shared__ int staged[CAP];
    __shared__ int pbase_sh;
    int b = blockIdx.x;
    int t = threadIdx.x;
    int s0 = bbase[b], s1 = bbase[b + 1];
    hist[t] = 0;
    __syncthreads();
    for (int i = s0 + t; i < s1; i += 256)
        atomicAdd(&hist[ebuf[i] >> 17], 1);
    __syncthreads();
    int v = hist[t];
    int pv = (v + 15) & ~15;
    sh[t] = pv;
    __syncthreads();
    for (int d = 1; d < 256; d <<= 1) {
        int u = (t >= d) ? sh[t - d] : 0;
        __syncthreads();
        sh[t] += u;
        __syncthreads();
    }
    int pexcl = sh[t] - pv;
    int pt = sh[255];
    if (t == 0) pbase_sh = atomicAdd(gpad, pt);
    __syncthreads();
    int pbase = pbase_sh;
    int node = b * NPB + t;
    if (node < N_NODES) nodei[node] = make_int2(v, pbase + pexcl);
    curs[t] = pexcl;
    __syncthreads();
    if (pt <= CAP) {
        for (int i = t; i < pt; i += 256) staged[i] = N_NODES;
        __syncthreads();
        for (int i = s0 + t; i < s1; i += 256) {
            int pk = ebuf[i];
            int pos = atomicAdd(&curs[pk >> 17], 1);
            staged[pos] = pk & 0x1FFFF;
        }
        __syncthreads();
        for (int i = t; i < pt; i += 256) csr_row[pbase + i] = staged[i];
    } else {
        for (int i = t; i < pt; i += 256) csr_row[pbase + i] = N_NODES;
        __syncthreads();
        for (int i = s0 + t; i < s1; i += 256) {
            int pk = ebuf[i];
            int pos = atomicAdd(&curs[pk >> 17], 1);
            csr_row[pbase + pos] = pk & 0x1FFFF;
        }
    }
}

// ---------------- pass 1: streaming pipelined gather + softmax + deg_term ----------
// Each wave: 16 contiguous nodes (same bucket) => contiguous padded csr stream.
// Pipeline: idx[g+2] and gathers[g+1] in flight while consuming group g.
__global__ __launch_bounds__(256, 4) void gather_softmax(
        const int2* __restrict__ nodei, const int* __restrict__ csr_row,
        const unsigned char* __restrict__ WT8, const float* __restrict__ MLPb,
        unsigned short* __restrict__ Sb, unsigned char* __restrict__ S8,
        float* __restrict__ dtp) {
    int lane = threadIdx.x & 63;
    int q = lane >> 4;
    int c = lane & 15;
    unsigned cb = (unsigned)c * 4u;
    int wib = __builtin_amdgcn_readfirstlane(threadIdx.x >> 6);
    int n0 = (blockIdx.x * 4 + wib) * 16;
    float dacc = 0.f;
    if (n0 < N_NODES) {
        int nvalid = min(16, N_NODES - n0);
        int2 di = nodei[n0 + min(c, nvalid - 1)];
        f32x4 bias = *(const f32x4*)(MLPb + c * 4);
        int ps0  = __shfl(di.y, 0, 64);
        int degL = __shfl(di.x, nvalid - 1, 64);
        int psL  = __shfl(di.y, nvalid - 1, 64);
        int G = ((psL + ((degL + 15) & ~15)) - ps0) >> 4;
        const int* cw = csr_row + ps0 + (q << 2);
        int4 iB = {0, 0, 0, 0};
        unsigned uA0 = 0, uA1 = 0, uA2 = 0, uA3 = 0;
        if (G > 0) {
            int4 iA = *(const int4*)(cw);
            uA0 = *(const unsigned*)(WT8 + (unsigned)iA.x * 64u + cb);
            uA1 = *(const unsigned*)(WT8 + (unsigned)iA.y * 64u + cb);
            uA2 = *(const unsigned*)(WT8 + (unsigned)iA.z * 64u + cb);
            uA3 = *(const unsigned*)(WT8 + (unsigned)iA.w * 64u + cb);
            int g1 = (G > 1) ? 1 : 0;
            iB = *(const int4*)(cw + (g1 << 4));
        }
        int g = 0;
        for (int k = 0; k < nvalid; ++k) {
            int deg = __shfl(di.x, k, 64);
            int gcnt = (deg + 15) >> 4;
            f32x4 acc = {0.f, 0.f, 0.f, 0.f};
            for (int tt = 0; tt < gcnt; ++tt) {
                int gn = g + 2; if (gn >= G) gn = G - 1;
                int4 iC = *(const int4*)(cw + (gn << 4));
                unsigned uB0 = *(const unsigned*)(WT8 + (unsigned)iB.x * 64u + cb);
                unsigned uB1 = *(const unsigned*)(WT8 + (unsigned)iB.y * 64u + cb);
                unsigned uB2 = *(const unsigned*)(WT8 + (unsigned)iB.z * 64u + cb);
                unsigned uB3 = *(const unsigned*)(WT8 + (unsigned)iB.w * 64u + cb);
                CONS4(acc);
                uA0 = uB0; uA1 = uB1; uA2 = uB2; uA3 = uB3; iB = iC;
                ++g;
            }
            // flush node n0+k
#pragma unroll
            for (int mm = 16; mm < 64; mm <<= 1) {
                acc.x += __shfl_xor(acc.x, mm, 64);
                acc.y += __shfl_xor(acc.y, mm, 64);
                acc.z += __shfl_xor(acc.z, mm, 64);
                acc.w += __shfl_xor(acc.w, mm, 64);
            }
            float ax = bias.x + acc.x * 0.03125f;
            float ay = bias.y + acc.y * 0.03125f;
            float az = bias.z + acc.z * 0.03125f;
            float aw = bias.w + acc.w * 0.03125f;
            float m4 = fmaxf(fmaxf(ax, ay), fmaxf(az, aw));
#pragma unroll
            for (int mm = 1; mm < 16; mm <<= 1) m4 = fmaxf(m4, __shfl_xor(m4, mm, 64));
            float ex = __expf(ax - m4), ey = __expf(ay - m4);
            float ez = __expf(az - m4), ew = __expf(aw - m4);
            float s4 = (ex + ey) + (ez + ew);
#pragma unroll
            for (int mm = 1; mm < 16; mm <<= 1) s4 += __shfl_xor(s4, mm, 64);
            float inv = 1.f / s4;
            float sx = ex * inv, sy = ey * inv, sz = ez * inv, sw = ew * inv;
            if (q == 0) {
                unsigned nidx = (unsigned)(n0 + k);
                unsigned lo = (unsigned)f2bf(sx) | ((unsigned)f2bf(sy) << 16);
                unsigned hi = (unsigned)f2bf(sz) | ((unsigned)f2bf(sw) << 16);
                *(uint2*)(Sb + nidx * 64u + cb) = make_uint2(lo, hi);
                int p8 = __builtin_amdgcn_cvt_pk_fp8_f32(sx * 64.f, sy * 64.f, 0, false);
                p8 = __builtin_amdgcn_cvt_pk_fp8_f32(sz * 64.f, sw * 64.f, p8, true);
                *(unsigned*)(S8 + nidx * 64u + cb) = (unsigned)p8;
            }
            dacc += (float)deg * ((sx * sx + sy * sy) + (sz * sz + sw * sw));
        }
    }
    dacc = wave_sum(dacc);   // 4x replicated across q-groups -> scale 0.25
    __shared__ float red[4];
    if (lane == 0) red[wib] = dacc * 0.25f;
    __syncthreads();
    if (threadIdx.x == 0) dtp[blockIdx.x] = red[0] + red[1] + red[2] + red[3];
}

// ---------------- fused tail, role-interleaved: 13 cut | 4 ss | 3 out per 20 ----
__global__ __launch_bounds__(256, 4) void fused_tail(
        const int2* __restrict__ nodei,
        const int* __restrict__ csr_row,
        const unsigned short* __restrict__ Sb, const unsigned char* __restrict__ S8,
        float* __restrict__ cutp, float* __restrict__ ssp,
        const float* __restrict__ x, const float* __restrict__ Weff,
        const float* __restrict__ beff, float* __restrict__ out) {
    __shared__ __align__(16) char sm[768 * 16 + 64];
    int t = threadIdx.x;
    int grp = blockIdx.x / 20;
    int r20 = blockIdx.x % 20;

    if (r20 < 13) {
        // ---- cut: streaming pipelined fp8 gather, 16 contiguous nodes/wave ----
        int vb = grp * 13 + r20;                  // 0..1572
        int lane = t & 63;
        int q = lane >> 4;
        int c = lane & 15;
        unsigned cb = (unsigned)c * 4u;
        int wib = __builtin_amdgcn_readfirstlane(t >> 6);
        int n0 = vb * 64 + wib * 16;
        float cacc = 0.f;
        if (n0 < N_NODES) {
            int nvalid = min(16, N_NODES - n0);
            int2 di = nodei[n0 + min(c, nvalid - 1)];
            int ps0  = __shfl(di.y, 0, 64);
            int degL = __shfl(di.x, nvalid - 1, 64);
            int psL  = __shfl(di.y, nvalid - 1, 64);
            int G = ((psL + ((degL + 15) & ~15)) - ps0) >> 4;
            const int* cw = csr_row + ps0 + (q << 2);
            uint2 suA = *(const uint2*)(Sb + (unsigned)n0 * 64u + cb);
            int4 iB = {0, 0, 0, 0};
            unsigned uA0 = 0, uA1 = 0, uA2 = 0, uA3 = 0;
            if (G > 0) {
                int4 iA = *(const int4*)(cw);
                uA0 = *(const unsigned*)(S8 + (unsigned)iA.x * 64u + cb);
                uA1 = *(const unsigned*)(S8 + (unsigned)iA.y * 64u + cb);
                uA2 = *(const unsigned*)(S8 + (unsigned)iA.z * 64u + cb);
                uA3 = *(const unsigned*)(S8 + (unsigned)iA.w * 64u + cb);
                int g1 = (G > 1) ? 1 : 0;
                iB = *(const int4*)(cw + (g1 << 4));
            }
            int g = 0;
            for (int k = 0; k < nvalid; ++k) {
                int deg = __shfl(di.x, k, 64);
                int gcnt = (deg + 15) >> 4;
                // prefetch next node's own S row
                uint2 suN = *(const uint2*)(Sb + (unsigned)(n0 + min(k + 1, nvalid - 1)) * 64u + cb);
                f32x4 acc = {0.f, 0.f, 0.f, 0.f};
                for (int tt = 0; tt < gcnt; ++tt) {
                    int gn = g + 2; if (gn >= G) gn = G - 1;
                    int4 iC = *(const int4*)(cw + (gn << 4));
                    unsigned uB0 = *(const unsigned*)(S8 + (unsigned)iB.x * 64u + cb);
                    unsigned uB1 = *(const unsigned*)(S8 + (unsigned)iB.y * 64u + cb);
                    unsigned uB2 = *(const unsigned*)(S8 + (unsigned)iB.z * 64u + cb);
                    unsigned uB3 = *(const unsigned*)(S8 + (unsigned)iB.w * 64u + cb);
                    CONS4(acc);
                    uA0 = uB0; uA1 = uB1; uA2 = uB2; uA3 = uB3; iB = iC;
                    ++g;
                }
                cacc += bf2f(suA.x) * acc.x + bf2f(suA.x >> 16) * acc.y
                      + bf2f(suA.y) * acc.z + bf2f(suA.y >> 16) * acc.w;
                suA = suN;
            }
        }
        cacc = wave_sum(cacc);
        float* red = (float*)sm;
        if (lane == 0) red[wib] = cacc * 0.015625f;
        __syncthreads();
        if (t == 0) cutp[vb] = red[0] + red[1] + red[2] + red[3];
    } else if (r20 < 17) {
        // ---- SS = S^T S via MFMA ----
        int bid2 = grp * 4 + (r20 - 13);          // 0..483
        unsigned short (*Sr)[66] = (unsigned short (*)[66])sm;
        int lane = t & 63;
        int w = t >> 6;
        int m = lane & 15;
        int quad = lane >> 4;
        int srow = t >> 3;
        int spart = t & 7;
        f32x4 a0 = {0.f,0.f,0.f,0.f}, a1 = {0.f,0.f,0.f,0.f};
        f32x4 a2 = {0.f,0.f,0.f,0.f}, a3 = {0.f,0.f,0.f,0.f};
        for (int base = bid2 * 32; base < N_NODES; base += SSP_BLOCKS * 32) {
            const uint4* g = (const uint4*)(Sb + (long long)(base + srow) * 64 + spart * 8);
            uint4 d = *g;
            __syncthreads();
            unsigned int* rowp = (unsigned int*)&Sr[srow][0];
            rowp[spart * 4 + 0] = d.x;
            rowp[spart * 4 + 1] = d.y;
            rowp[spart * 4 + 2] = d.z;
            rowp[spart * 4 + 3] = d.w;
            __syncthreads();
            short8 f0, f1, f2, f3;
#pragma unroll
            for (int j = 0; j < 8; ++j) {
                int k = quad * 8 + j;
                f0[j] = (short)Sr[k][m];
                f1[j] = (short)Sr[k][16 + m];
                f2[j] = (short)Sr[k][32 + m];
                f3[j] = (short)Sr[k][48 + m];
            }
            short8 fa = (w == 0) ? f0 : (w == 1) ? f1 : (w == 2) ? f2 : f3;
            a0 = __builtin_amdgcn_mfma_f32_16x16x32_bf16(fa, f0, a0, 0, 0, 0);
            a1 = __builtin_amdgcn_mfma_f32_16x16x32_bf16(fa, f1, a1, 0, 0, 0);
            a2 = __builtin_amdgcn_mfma_f32_16x16x32_bf16(fa, f2, a2, 0, 0, 0);
            a3 = __builtin_amdgcn_mfma_f32_16x16x32_bf16(fa, f3, a3, 0, 0, 0);
        }
        float* dst = ssp + (size_t)bid2 * 4096;
#pragma unroll
        for (int r = 0; r < 4; ++r) {
            int row = w * 16 + quad * 4 + r;
            dst[row * 64 +  0 + m] = a0[r];
            dst[row * 64 + 16 + m] = a1[r];
            dst[row * 64 + 32 + m] = a2[r];
            dst[row * 64 + 48 + m] = a3[r];
        }
    } else {
        // ---- out: logits + log_softmax (grid-stride over rows) ----
        int obid = grp * 3 + (r20 - 17);          // 0..362
        float4* Wsh = (float4*)sm;
        float* bsh = (float*)(sm + 768 * 16);
        const float4* W4 = (const float4*)Weff;
        for (int i = t; i < 768; i += 256) Wsh[i] = W4[i];
        if (t < 16) bsh[t] = beff[t];
        __syncthreads();
        for (int r = obid * 256 + t; r < N_NODES; r += OUTG_BLOCKS * 256) {
            float4 p0 = make_float4(bsh[0], bsh[1], bsh[2], bsh[3]);
            float4 p1 = make_float4(bsh[4], bsh[5], bsh[6], bsh[7]);
            float4 p2 = make_float4(bsh[8], bsh[9], bsh[10], bsh[11]);
            float4 p3 = make_float4(bsh[12], bsh[13], bsh[14], bsh[15]);
            const float4* xr = (const float4*)(x + (long long)r * IN_C);
#pragma unroll 8
            for (int j = 0; j < 32; ++j) {
                float4 xv = xr[j];
                int k = j * 4;
                float xs[4] = {xv.x, xv.y, xv.z, xv.w};
#pragma unroll
                for (int c = 0; c < 4; ++c) {
                    float s = xs[c];
                    float4 w0 = Wsh[(k + c) * 4 + 0];
                    float4 w1 = Wsh[(k + c) * 4 + 1];
                    float4 w2 = Wsh[(k + c) * 4 + 2];
                    float4 w3 = Wsh[(k + c) * 4 + 3];
                    FMA4(p0, s, w0); FMA4(p1, s, w1); FMA4(p2, s, w2); FMA4(p3, s, w3);
                }
            }
            const uint2* sr = (const uint2*)(Sb + (long long)r * 64);
#pragma unroll 8
            for (int j = 0; j < 16; ++j) {
                uint2 u = sr[j];
                float xs[4] = {bf2f(u.x), bf2f(u.x >> 16), bf2f(u.y), bf2f(u.y >> 16)};
                int k = IN_C + j * 4;
#pragma unroll
                for (int c = 0; c < 4; ++c) {
                    float s = xs[c];
                    float4 w0 = Wsh[(k + c) * 4 + 0];
                    float4 w1 = Wsh[(k + c) * 4 + 1];
                    float4 w2 = Wsh[(k + c) * 4 + 2];
                    float4 w3 = Wsh[(k + c) * 4 + 3];
                    FMA4(p0, s, w0); FMA4(p1, s, w1); FMA4(p2, s, w2); FMA4(p3, s, w3);
                }
            }
            float m = fmaxf(fmaxf(fmaxf(p0.x, p0.y), fmaxf(p0.z, p0.w)),
                            fmaxf(fmaxf(fmaxf(p1.x, p1.y), fmaxf(p1.z, p1.w)),
                                  fmaxf(fmaxf(fmaxf(p2.x, p2.y), fmaxf(p2.z, p2.w)),
                                        fmaxf(fmaxf(p3.x, p3.y), fmaxf(p3.z, p3.w)))));
            float sum = __expf(p0.x - m) + __expf(p0.y - m) + __expf(p0.z - m) + __expf(p0.w - m)
                      + __expf(p1.x - m) + __expf(p1.y - m) + __expf(p1.z - m) + __expf(p1.w - m)
                      + __expf(p2.x - m) + __expf(p2.y - m) + __expf(p2.z - m) + __expf(p2.w - m)
                      + __expf(p3.x - m) + __expf(p3.y - m) + __expf(p3.z - m) + __expf(p3.w - m);
            float lse = m + logf(sum);
            float4* o4 = (float4*)(out + (long long)r * OUT_C);
            o4[0] = make_float4(p0.x - lse, p0.y - lse, p0.z - lse, p0.w - lse);
            o4[1] = make_float4(p1.x - lse, p1.y - lse, p1.z - lse, p1.w - lse);
            o4[2] = make_float4(p2.x - lse, p2.y - lse, p2.z - lse, p2.w - lse);
            o4[3] = make_float4(p3.x - lse, p3.y - lse, p3.z - lse, p3.w - lse);
        }
    }
}

__global__ void reduce_ss(const float* __restrict__ ssp, float* __restrict__ SS) {
    int e = blockIdx.x * blockDim.x + threadIdx.x;
    float s = 0.f;
    for (int p = 0; p < SSP_BLOCKS; ++p) s += ssp[(size_t)p * 4096 + e];
    SS[e] = s;
}

// ---------------- scalar losses ----------------
__global__ void scalars_kernel(const float* __restrict__ cutp, const float* __restrict__ dtp,
                               const float* __restrict__ SS, float* __restrict__ out) {
    __shared__ float red[256];
    int t = threadIdx.x;
    float c = 0.f;
    for (int i = t; i < CUT_VB; i += 256) c += cutp[i];
    red[t] = c; __syncthreads();
    for (int s = 128; s; s >>= 1) { if (t < s) red[t] += red[t + s]; __syncthreads(); }
    float cut = red[0]; __syncthreads();

    float d = 0.f;
    for (int i = t; i < GATHER_BLOCKS; i += 256) d += dtp[i];
    red[t] = d; __syncthreads();
    for (int s = 128; s; s >>= 1) { if (t < s) red[t] += red[t + s]; __syncthreads(); }
    float dterm = red[0]; __syncthreads();

    float ss[16];
    float sq = 0.f;
#pragma unroll
    for (int j = 0; j < 16; ++j) { ss[j] = SS[t * 16 + j]; sq += ss[j] * ss[j]; }
    red[t] = sq; __syncthreads();
    for (int s = 128; s; s >>= 1) { if (t < s) red[t] += red[t + s]; __syncthreads(); }
    float nrm = sqrtf(red[0]); __syncthreads();

    float osq = 0.f;
#pragma unroll
    for (int j = 0; j < 16; ++j) {
        int idx = t * 16 + j;
        float v = ss[j] / nrm - ((idx % 65 == 0) ? 0.125f : 0.f);
        osq += v * v;
    }
    red[t] = osq; __syncthreads();
    for (int s = 128; s; s >>= 1) { if (t < s) red[t] += red[t + s]; __syncthreads(); }
    if (t == 0) {
        float loss = -(cut / dterm) + sqrtf(red[0]);
        out[(long long)N_NODES * OUT_C] = loss;
    }
}

extern "C" void kernel_launch(void* const* d_in, const int* in_sizes, int n_in,
                              void* d_out, int out_size, void* d_ws, size_t ws_size,
                              hipStream_t stream) {
    const float* x     = (const float*)d_in[0];
    const int*   ei    = (const int*)d_in[1];
    const float* MLPW  = (const float*)d_in[2];
    const float* MLPb  = (const float*)d_in[3];
    const float* mlpxW = (const float*)d_in[4];
    const float* mlpxb = (const float*)d_in[5];
    const float* finW  = (const float*)d_in[6];
    const float* finb  = (const float*)d_in[7];
    float* out = (float*)d_out;
    char* ws = (char*)d_ws;

    unsigned char*  WT8 = (unsigned char*)ws;                                 // (N+1)*64
    unsigned char*  S8  = (unsigned char*)(ws + (size_t)(N_NODES + 1) * 64);  // (N+1)*64
    unsigned short* Sb  = (unsigned short*)(ws + (size_t)(N_NODES + 1) * 128);// N*64*2
    char* p = ws + (size_t)(N_NODES + 1) * 128 + (size_t)N_NODES * 128;
    float* ssp  = (float*)p;                                 // 512*4096 f (484 used)
    float* SS   = ssp + (size_t)SSP_ALLOC * 4096;            // 4096
    float* Weff = SS + 4096;                                 // 3072
    float* beff = Weff + 192 * 16;                           // 16
    float* cutp = beff + 16;                                 // 2048 (1573 used)
    float* dtp  = cutp + 2048;                               // 2048 (1563 used)
    int* ebuf    = (int*)(dtp + 2048);                       // E
    int* csr_row = ebuf + N_EDGES;                           // E + 16N (padded)
    int2* nodei  = (int2*)(csr_row + N_EDGES + 16 * N_NODES);// N int2 (deg, pstart)
    int* bcnt    = (int*)(nodei + N_NODES);                  // NBUCKET+1
    int* bbase   = bcnt + NBUCKET + 1;                       // NBUCKET+1
    int* bcur    = bbase + NBUCKET + 1;                      // NBUCKET
    int* gpad    = bcur + NBUCKET;                           // 1

    hipLaunchKernelGGL(prep_weff, dim3(16), dim3(256), 0, stream,
                       mlpxW, mlpxb, finW, finb, Weff, beff, bcnt, WT8, S8, gpad);
    hipLaunchKernelGGL(fused_prep, dim3(TRANS_BLOCKS + NTILE), dim3(256), 0, stream,
                       MLPW, WT8, ei, bcnt);
    hipLaunchKernelGGL(bucket_scan, dim3(1), dim3(512), 0, stream, bcnt, bbase, bcur);
    hipLaunchKernelGGL(bucket_scatter, dim3(NTILE), dim3(256), 0, stream, ei, bcur, ebuf);
    hipLaunchKernelGGL(csr_build, dim3(NBUCKET), dim3(256), 0, stream,
                       ebuf, bbase, nodei, csr_row, gpad);
    hipLaunchKernelGGL(gather_softmax, dim3(GATHER_BLOCKS), dim3(256), 0, stream,
                       nodei, csr_row, WT8, MLPb, Sb, S8, dtp);
    hipLaunchKernelGGL(fused_tail, dim3(TAIL_BLOCKS), dim3(256), 0, stream,
                       nodei, csr_row, Sb, S8, cutp, ssp, x, Weff, beff, out);
    hipLaunchKernelGGL(reduce_ss, dim3(16), dim3(256), 0, stream, ssp, SS);
    hipLaunchKernelGGL(scalars_kernel, dim3(1), dim3(256), 0, stream, cutp, dtp, SS, out);
}